// Round 15
// baseline (307.667 us; speedup 1.0000x reference)
//
#include <hip/hip_runtime.h>
#include <stdint.h>

typedef unsigned short u16;
typedef short short8 __attribute__((ext_vector_type(8)));
typedef float f32x4 __attribute__((ext_vector_type(4)));
typedef uint32_t u32x4 __attribute__((ext_vector_type(4)));

#define S_LEN 2048
#define NQH 32
#define NKH 8
#define DHD 64
#define MNEG -1.0e30f

__device__ __forceinline__ float b2f(u16 u){
  union { uint32_t i; float f; } c; c.i = ((uint32_t)u) << 16; return c.f;
}
__device__ __forceinline__ u16 f2b(float f){
  union { float f; uint32_t i; } c; c.f = f;
  uint32_t r = c.i + 0x7fffu + ((c.i >> 16) & 1u);
  return (u16)(r >> 16);
}
__device__ __forceinline__ uint32_t cvt_pk_bf16(float lo, float hi){
  uint32_t r;
  asm("v_cvt_pk_bf16_f32 %0, %1, %2" : "=v"(r) : "v"(lo), "v"(hi));
  return r;
}
__device__ __forceinline__ void gload_lds16(const void* g, void* l){
  __builtin_amdgcn_global_load_lds((const __attribute__((address_space(1))) uint32_t*)g,
                                   (__attribute__((address_space(3))) uint32_t*)l, 16, 0, 0);
}

// ------- fused fp32 -> bf16 convert (hs | Wqkv | Wo) + cos/sin bf16 pack -------
__global__ __launch_bounds__(256) void cvt_all(const float* __restrict__ hs,
                                               const float* __restrict__ wq,
                                               const float* __restrict__ wo,
                                               const float* __restrict__ cosp,
                                               const float* __restrict__ sinp,
                                               u16* __restrict__ hsB,
                                               u16* __restrict__ wqB,
                                               u16* __restrict__ woB,
                                               uint32_t* __restrict__ csB){
  int i = blockIdx.x * 256 + threadIdx.x;       // 4718592 f32x4 + 32768 cs-x4
  if (i >= 4718592){
    int off = i - 4718592;                      // 0..32767
    float4 c = ((const float4*)cosp)[off];
    float4 s = ((const float4*)sinp)[off];
    u32x4 o = { (uint32_t)f2b(c.x) | ((uint32_t)f2b(s.x) << 16),
                (uint32_t)f2b(c.y) | ((uint32_t)f2b(s.y) << 16),
                (uint32_t)f2b(c.z) | ((uint32_t)f2b(s.z) << 16),
                (uint32_t)f2b(c.w) | ((uint32_t)f2b(s.w) << 16) };
    ((u32x4*)csB)[off] = o;
    return;
  }
  const float* src; u16* dst; int off;
  if (i < 2097152)      { src = hs; dst = hsB; off = i; }
  else if (i < 3670016) { src = wq; dst = wqB; off = i - 2097152; }
  else                  { src = wo; dst = woB; off = i - 3670016; }
  float4 v = ((const float4*)src)[off];
  uint2 o;
  o.x = (uint32_t)f2b(v.x) | ((uint32_t)f2b(v.y) << 16);
  o.y = (uint32_t)f2b(v.z) | ((uint32_t)f2b(v.w) << 16);
  ((uint2*)dst)[off] = o;
}

// ---- GEMM staging macro: 8 gload_lds (A-tile 4, B-tile 4) into buffer BSEL (0..2) ----
#define GSTAGE(KT, BSEL) do { \
    _Pragma("unroll") \
    for (int i_ = 0; i_ < 4; ++i_){ \
      const int row_ = (i_ * 4 + w) * 8 + srow; \
      const int gc_ = ((sc ^ (row_ & 7)) << 4); \
      gload_lds16((const char*)A + (size_t)(m0 + row_) * ldb + (size_t)(KT) * 128 + gc_, \
                  (char*)lA + (BSEL) * 16384 + row_ * 128 + sc * 16); \
    } \
    _Pragma("unroll") \
    for (int i_ = 0; i_ < 4; ++i_){ \
      const int row_ = (i_ * 4 + w) * 8 + srow; \
      const int gc_ = ((sc ^ (row_ & 7)) << 4); \
      gload_lds16((const char*)Bm + (size_t)(n0 + row_) * ldb + (size_t)(KT) * 128 + gc_, \
                  (char*)lB + (BSEL) * 16384 + row_ * 128 + sc * 16); \
    } \
  } while (0)

// ---- shared compute body: 32 MFMA on buffer CUR ----
#define GCOMPUTE(CUR) do { \
    _Pragma("unroll") \
    for (int kk = 0; kk < 2; ++kk){ \
      short8 af[4], bfr[4]; \
      _Pragma("unroll") \
      for (int mi = 0; mi < 4; ++mi){ \
        const int row = wm * 64 + mi * 16 + lc; \
        const int cc = (kk * 4 + lg) ^ (row & 7); \
        af[mi] = *(const short8*)((const char*)lA + (CUR) * 16384 + row * 128 + cc * 16); \
      } \
      _Pragma("unroll") \
      for (int ni = 0; ni < 4; ++ni){ \
        const int row = wn * 64 + ni * 16 + lc; \
        const int cc = (kk * 4 + lg) ^ (row & 7); \
        bfr[ni] = *(const short8*)((const char*)lB + (CUR) * 16384 + row * 128 + cc * 16); \
      } \
      _Pragma("unroll") \
      for (int mi = 0; mi < 4; ++mi) \
        _Pragma("unroll") \
        for (int ni = 0; ni < 4; ++ni) \
          acc[mi][ni] = __builtin_amdgcn_mfma_f32_16x16x32_bf16(af[mi], bfr[ni], acc[mi][ni], 0, 0, 0); \
    } \
  } while (0)

// ---------------- bf16 GEMM (f32 out): C = A * B^T, 3-buffer 2-ahead pipeline ----------------
// Single barrier per K-iter: { vmcnt(8); barrier; STAGE(kt+2 -> (kt+2)%3);
// compute((kt)%3) }. Tile kt issued 2 iters before use -> ~2 compute phases of
// latency cover; vmcnt(8) certifies it. LDS 96KB -> 1 block/CU.
__global__ __launch_bounds__(256)
void gemm_bt_f32(const u16* __restrict__ A, const u16* __restrict__ Bm,
                 float* __restrict__ Cp, int N, int K, int nbx, int nwg)
{
  __shared__ alignas(16) u16 lA[3 * 128 * 64];
  __shared__ alignas(16) u16 lB[3 * 128 * 64];
  const int id = blockIdx.x;
  const int swz = (id & 7) * (nwg >> 3) + (id >> 3);
  const int m0 = (swz / nbx) * 128, n0 = (swz % nbx) * 128;
  const int tid = threadIdx.x;
  const int w = tid >> 6, l = tid & 63;
  const int lg = l >> 4, lc = l & 15;
  const int wm = w >> 1, wn = w & 1;
  const int srow = l >> 3, sc = l & 7;
  const size_t ldb = (size_t)K * 2;   // row bytes
  f32x4 acc[4][4] = {};
  const int kiters = K >> 6;

  GSTAGE(0, 0);
  GSTAGE(1, 1);
  for (int kt = 0; kt < kiters; ++kt){
    if (kt + 1 < kiters) asm volatile("s_waitcnt vmcnt(8)" ::: "memory");
    else                 asm volatile("s_waitcnt vmcnt(0)" ::: "memory");
    __builtin_amdgcn_s_barrier();
    if (kt + 2 < kiters) GSTAGE(kt + 2, (kt + 2) % 3);
    const int cur = kt % 3;
    GCOMPUTE(cur);
  }
  const int r0 = m0 + wm * 64 + lg * 4;
  const int c0 = n0 + wn * 64 + lc;
#pragma unroll
  for (int mi = 0; mi < 4; ++mi)
#pragma unroll
    for (int ni = 0; ni < 4; ++ni)
#pragma unroll
      for (int j = 0; j < 4; ++j)
        Cp[(size_t)(r0 + mi * 16 + j) * (size_t)N + (size_t)(c0 + ni * 16)] = acc[mi][ni][j];
}

// ---------------- GEMM1 + fused RoPE/scale epilogue (3-buffer pipeline) ----------------
// qkv = hs * Wqkv^T (M=4096, N=3072, K=2048). Epilogue: per thread one head,
// RoPE partner d^32 = acc[mi][ni^2][j] (same thread). Q *1.2*kscale*phs ->
// Qb; K *1.2 -> Kb; V raw -> Vraw[b][s][8][64]. cs table: bf16 cos|sin.
__global__ __launch_bounds__(256)
void gemm1_rope(const u16* __restrict__ A, const u16* __restrict__ Bm,
                const uint32_t* __restrict__ cs, const float* __restrict__ phs,
                u16* __restrict__ Qo, u16* __restrict__ Ko, u16* __restrict__ Vraw)
{
  __shared__ alignas(16) u16 lA[3 * 128 * 64];
  __shared__ alignas(16) u16 lB[3 * 128 * 64];
  const int id = blockIdx.x;
  const int swz = (id & 7) * 96 + (id >> 3);   // nwg = 768
  const int m0 = (swz / 24) * 128, n0 = (swz % 24) * 128;
  const int tid = threadIdx.x;
  const int w = tid >> 6, l = tid & 63;
  const int lg = l >> 4, lc = l & 15;
  const int wm = w >> 1, wn = w & 1;
  const int srow = l >> 3, sc = l & 7;
  const size_t ldb = 4096;            // K=2048 row bytes
  f32x4 acc[4][4] = {};

  GSTAGE(0, 0);
  GSTAGE(1, 1);
  for (int kt = 0; kt < 32; ++kt){
    if (kt + 1 < 32) asm volatile("s_waitcnt vmcnt(8)" ::: "memory");
    else             asm volatile("s_waitcnt vmcnt(0)" ::: "memory");
    __builtin_amdgcn_s_barrier();
    if (kt + 2 < 32) GSTAGE(kt + 2, (kt + 2) % 3);
    const int cur = kt % 3;
    GCOMPUTE(cur);
  }
  const int r0 = m0 + wm * 64 + lg * 4;
  const int c0 = n0 + wn * 64 + lc;
  const int head = (n0 + wn * 64) >> 6;          // one head per thread
  const int b = m0 >> 11;
  if (head < 40){
    const float scale = (head < NQH) ? 1.2f * 0.18033688011112042f * phs[b * NQH + head] : 1.2f;
    u16* dstbase = (head < NQH)
        ? (Qo + ((size_t)(b * NQH + head) * S_LEN) * 64)
        : (Ko + ((size_t)(b * NKH + (head - NQH)) * S_LEN) * 64);
#pragma unroll
    for (int mi = 0; mi < 4; ++mi)
#pragma unroll
      for (int j = 0; j < 4; ++j){
        const int s = (r0 + mi * 16 + j) & 2047;
        const uint32_t* csrow = cs + s * 64;
        float xs[4] = {acc[mi][0][j], acc[mi][1][j], acc[mi][2][j], acc[mi][3][j]};
#pragma unroll
        for (int ni = 0; ni < 4; ++ni){
          const int d = lc + ni * 16;
          const uint32_t csv = csrow[d];
          const float cv = b2f((u16)(csv & 0xffff));
          const float sv = b2f((u16)(csv >> 16));
          const float sgn = (ni < 2) ? -1.f : 1.f;
          const float v = (xs[ni] * cv + sgn * xs[ni ^ 2] * sv) * scale;
          dstbase[(size_t)s * 64 + d] = f2b(v);
        }
      }
  } else {
    // V heads -> compact Vraw[b][s][8][64]
#pragma unroll
    for (int mi = 0; mi < 4; ++mi)
#pragma unroll
      for (int ni = 0; ni < 4; ++ni)
#pragma unroll
        for (int j = 0; j < 4; ++j){
          const int r = r0 + mi * 16 + j;
          Vraw[(size_t)r * 512 + (c0 + ni * 16 - 2560)] = f2b(acc[mi][ni][j]);
        }
  }
}
#undef GSTAGE
#undef GCOMPUTE

// ---------------- V transpose + k-permute: Vraw[b][s][8][64] -> VT[b][kh][d][t*128+k] ----------------
// VT[d][t*128+k] = V[s = t*128 + h(k)][d], h(k) = 32*(k>>5) + 16*((k>>2)&1)
// + 4*((k>>3)&3) + (k&3) -> zero-shuffle PV in attention.
__global__ __launch_bounds__(256)
void vtrans(const u16* __restrict__ Vraw, u16* __restrict__ VT)
{
  int bid = blockIdx.x;                 // (b*8+kh)*16 + t
  int t = bid & 15, kh = (bid >> 4) & 7, b = bid >> 7;
  __shared__ u16 vlds[128][72];
  int tid = threadIdx.x;
  {
    int r = tid >> 1, half = tid & 1;
    const u16* src = Vraw + (((size_t)(b * S_LEN + t * 128 + r) * 8 + kh) << 6) + half * 32;
    uint4 a0 = *(const uint4*)(src);
    uint4 a1 = *(const uint4*)(src + 8);
    uint4 a2 = *(const uint4*)(src + 16);
    uint4 a3 = *(const uint4*)(src + 24);
    *(uint4*)&vlds[r][half * 32]      = a0;
    *(uint4*)&vlds[r][half * 32 + 8]  = a1;
    *(uint4*)&vlds[r][half * 32 + 16] = a2;
    *(uint4*)&vlds[r][half * 32 + 24] = a3;
  }
  __syncthreads();
  const int d = tid >> 2, kk2 = tid & 3;
  u16* dst = VT + ((size_t)(b * NKH + kh) * 64 + d) * S_LEN + t * 128 + kk2 * 32;
#pragma unroll
  for (int j = 0; j < 4; ++j){          // j = lg
    u16 o[8];
#pragma unroll
    for (int e = 0; e < 8; ++e){
      const int hk = kk2 * 32 + ((e >> 2) << 4) + j * 4 + (e & 3);
      o[e] = vlds[hk][d];
    }
    uint4 ov = { (uint32_t)o[0] | ((uint32_t)o[1] << 16), (uint32_t)o[2] | ((uint32_t)o[3] << 16),
                 (uint32_t)o[4] | ((uint32_t)o[5] << 16), (uint32_t)o[6] | ((uint32_t)o[7] << 16) };
    *(uint4*)(dst + j * 8) = ov;
  }
}

// ---------------- attention helper: softmax + pack (zero-shuffle PV) ----------------
__device__ __forceinline__ void proc_chunk(f32x4 (&sv)[8], float& mrow, float& lsum,
                                           f32x4 (&o)[4], uint32_t (&pw)[4][4],
                                           const int lg, const int lc,
                                           const bool diag, const int qloc)
{
  if (diag){
#pragma unroll
    for (int nj = 0; nj < 8; ++nj)
#pragma unroll
      for (int jj = 0; jj < 4; ++jj){
        const int kloc = nj * 16 + lg * 4 + jj;
        if (kloc > qloc) sv[nj][jj] = MNEG;
      }
  }
  float mu = sv[0][0];
#pragma unroll
  for (int nj = 0; nj < 8; ++nj)
#pragma unroll
    for (int jj = 0; jj < 4; ++jj) mu = fmaxf(mu, sv[nj][jj]);
  mu = fmaxf(mu, __shfl_xor(mu, 16));
  mu = fmaxf(mu, __shfl_xor(mu, 32));
  if (!__all(mu <= mrow + 11.54f)){
    const float mnew = fmaxf(mrow, mu);
    const float sf = __builtin_amdgcn_exp2f(mrow - mnew);
    mrow = mnew;
    lsum *= sf;
#pragma unroll
    for (int dn = 0; dn < 4; ++dn)
#pragma unroll
      for (int jj = 0; jj < 4; ++jj) o[dn][jj] *= sf;
  }
  const float mcur = mrow;
  float ps = 0.f;
#pragma unroll
  for (int nj = 0; nj < 8; ++nj)
#pragma unroll
    for (int jj = 0; jj < 4; ++jj){
      const float pv = __builtin_amdgcn_exp2f(sv[nj][jj] - mcur);
      sv[nj][jj] = pv;
      ps += pv;
    }
  lsum += ps;
#pragma unroll
  for (int kk2 = 0; kk2 < 4; ++kk2){
    pw[kk2][0] = cvt_pk_bf16(sv[kk2 * 2][0],     sv[kk2 * 2][1]);
    pw[kk2][1] = cvt_pk_bf16(sv[kk2 * 2][2],     sv[kk2 * 2][3]);
    pw[kk2][2] = cvt_pk_bf16(sv[kk2 * 2 + 1][0], sv[kk2 * 2 + 1][1]);
    pw[kk2][3] = cvt_pk_bf16(sv[kk2 * 2 + 1][2], sv[kk2 * 2 + 1][3]);
  }
}

__device__ __forceinline__ short8 pw_frag(const uint32_t* pw){
  u32x4 v = { pw[0], pw[1], pw[2], pw[3] };
  return __builtin_bit_cast(short8, v);
}

// ---------------- causal GQA flash attention (R11-verified) ----------------
__global__ __launch_bounds__(512, 2)
void attn_kernel(const u16* __restrict__ Q, const u16* __restrict__ Kr,
                 const u16* __restrict__ VT, u16* __restrict__ Ao)
{
  int bid = blockIdx.x;
  int p  = bid & 15;
  int gp = (bid >> 4) & 1;
  int kh = (bid >> 5) & 7;
  int b  = bid >> 8;
  const int qt0 = p, qt1 = 31 - p;

  __shared__ alignas(16) u16 lK[2][128 * 64];
  __shared__ alignas(16) u16 lV[2][64 * 128];

  const int tid = threadIdx.x;
  const int hh = tid >> 8;
  const int h  = kh * 4 + gp * 2 + hh;
  const int w  = (tid >> 6) & 3;
  const int l  = tid & 63;
  const int lg = l >> 4, lc = l & 15;

  short8 qf[2][2];
  {
    const u16* qbase = Q + ((size_t)(b * NQH + h) * S_LEN) * 64;
#pragma unroll
    for (int kk = 0; kk < 2; ++kk){
      qf[0][kk] = *(const short8*)(qbase + (size_t)(qt0 * 64 + w * 16 + lc) * 64 + kk * 32 + lg * 8);
      qf[1][kk] = *(const short8*)(qbase + (size_t)(qt1 * 64 + w * 16 + lc) * 64 + kk * 32 + lg * 8);
    }
  }

  const u16* Kb = Kr + (size_t)(b * NKH + kh) * S_LEN * 64;
  const u16* Vb = VT + (size_t)(b * NKH + kh) * 64 * S_LEN;

  f32x4 o[2][4] = {};
  float mrow[2] = {MNEG, MNEG};
  float lsum[2] = {0.f, 0.f};

  const int nt = (qt1 >> 1) + 1;
  const int nt0 = qt0 >> 1;

#define STAGE(T, BSEL) do { \
    _Pragma("unroll") \
    for (int i_ = 0; i_ < 2; ++i_){ \
      const int row_ = i_ * 64 + (tid >> 3); \
      const int ch_  = tid & 7; \
      const int gc_  = ((ch_ ^ (row_ & 7)) << 4); \
      gload_lds16((const char*)(Kb + (size_t)((T) * 128 + row_) * 64) + gc_, \
                  (char*)lK[BSEL] + row_ * 128 + ch_ * 16); \
    } \
    _Pragma("unroll") \
    for (int i_ = 0; i_ < 2; ++i_){ \
      const int row_ = i_ * 32 + (tid >> 4); \
      const int ch_  = tid & 15; \
      const int gc_  = ((ch_ ^ (row_ & 15)) << 4); \
      gload_lds16((const char*)(Vb + (size_t)row_ * S_LEN + (T) * 128) + gc_, \
                  (char*)lV[BSEL] + row_ * 256 + ch_ * 16); \
    } \
  } while (0)

  STAGE(0, 0);

  for (int t = 0; t < nt; ++t){
    const int cur = t & 1;
    const bool act0 = (t <= nt0);
    if (t + 1 < nt){
      STAGE(t + 1, cur ^ 1);
      asm volatile("s_waitcnt vmcnt(4)" ::: "memory");
    } else {
      asm volatile("s_waitcnt vmcnt(0)" ::: "memory");
    }
    __builtin_amdgcn_s_barrier();

    f32x4 sv[2][8] = {};
    __builtin_amdgcn_s_setprio(1);
#pragma unroll
    for (int kk = 0; kk < 2; ++kk){
      short8 kf[8];
#pragma unroll
      for (int nj = 0; nj < 8; ++nj){
        const int row = nj * 16 + lc;
        const int cc = (kk * 4 + lg) ^ (row & 7);
        kf[nj] = *(const short8*)((const char*)lK[cur] + row * 128 + cc * 16);
      }
      if (act0)
#pragma unroll
        for (int nj = 0; nj < 8; ++nj)
          sv[0][nj] = __builtin_amdgcn_mfma_f32_16x16x32_bf16(kf[nj], qf[0][kk], sv[0][nj], 0, 0, 0);
#pragma unroll
      for (int nj = 0; nj < 8; ++nj)
        sv[1][nj] = __builtin_amdgcn_mfma_f32_16x16x32_bf16(kf[nj], qf[1][kk], sv[1][nj], 0, 0, 0);
    }
    __builtin_amdgcn_s_setprio(0);

    uint32_t pw[2][4][4];
    if (act0)
      proc_chunk(sv[0], mrow[0], lsum[0], o[0], pw[0], lg, lc,
                 t == (qt0 >> 1), (qt0 & 1) * 64 + w * 16 + lc);
    proc_chunk(sv[1], mrow[1], lsum[1], o[1], pw[1], lg, lc,
               t == (qt1 >> 1), (qt1 & 1) * 64 + w * 16 + lc);

    __builtin_amdgcn_s_setprio(1);
#pragma unroll
    for (int kk2 = 0; kk2 < 4; ++kk2){
      short8 vf[4];
#pragma unroll
      for (int dn = 0; dn < 4; ++dn){
        const int row = dn * 16 + lc;
        const int cc = (kk2 * 4 + lg) ^ (row & 15);
        vf[dn] = *(const short8*)((const char*)lV[cur] + row * 256 + cc * 16);
      }
      if (act0){
        const short8 pb0 = pw_frag(pw[0][kk2]);
#pragma unroll
        for (int dn = 0; dn < 4; ++dn)
          o[0][dn] = __builtin_amdgcn_mfma_f32_16x16x32_bf16(vf[dn], pb0, o[0][dn], 0, 0, 0);
      }
      const short8 pb1 = pw_frag(pw[1][kk2]);
#pragma unroll
      for (int dn = 0; dn < 4; ++dn)
        o[1][dn] = __builtin_amdgcn_mfma_f32_16x16x32_bf16(vf[dn], pb1, o[1][dn], 0, 0, 0);
    }
    __builtin_amdgcn_s_setprio(0);
    __builtin_amdgcn_s_barrier();
  }
#undef STAGE

#pragma unroll
  for (int c = 0; c < 2; ++c){
    const int qt = c ? qt1 : qt0;
    float ls = lsum[c];
    ls += __shfl_xor(ls, 16);
    ls += __shfl_xor(ls, 32);
    const float inv = 1.f / ls;
    const int sq = qt * 64 + w * 16 + lc;
#pragma unroll
    for (int dn = 0; dn < 4; ++dn){
      uint2 pk;
      pk.x = cvt_pk_bf16(o[c][dn][0] * inv, o[c][dn][1] * inv);
      pk.y = cvt_pk_bf16(o[c][dn][2] * inv, o[c][dn][3] * inv);
      const int col = h * 64 + dn * 16 + lg * 4;
      *(uint2*)&Ao[(size_t)(b * S_LEN + sq) * 2048 + col] = pk;
    }
  }
}

// ---------------- launcher ----------------
extern "C" void kernel_launch(void* const* d_in, const int* in_sizes, int n_in,
                              void* d_out, int out_size, void* d_ws, size_t ws_size,
                              hipStream_t stream)
{
  const float* cosT = (const float*)d_in[0];
  const float* sinT = (const float*)d_in[1];
  const float* hs   = (const float*)d_in[2];
  const float* phs  = (const float*)d_in[3];
  const float* Wqkv = (const float*)d_in[4];
  const float* Wo   = (const float*)d_in[5];
  float* out = (float*)d_out;
  char* ws = (char*)d_ws;

  u16* hsB   = (u16*)(ws);               // 16,777,216 B (aliased as attn_out later)
  u16* WqkvB = (u16*)(ws + 16777216);    // 12,582,912 B
  u16* WoB   = (u16*)(ws + 29360128);    //  8,388,608 B
  u16* Vraw  = (u16*)(ws + 37748736);    //  4,194,304 B
  u16* Qb    = (u16*)(ws + 41943040);    // 16,777,216 B
  u16* Kb    = (u16*)(ws + 58720256);    //  4,194,304 B
  u16* VTb   = (u16*)(ws + 62914560);    //  4,194,304 B
  uint32_t* csB = (uint32_t*)(ws + 67108864); // 524,288 B (total 67,633,152 B)
  u16* Ao    = hsB;                      // hsB dead after GEMM1

  cvt_all<<<18560, 256, 0, stream>>>(hs, Wqkv, Wo, cosT, sinT, hsB, WqkvB, WoB, csB);
  gemm1_rope<<<768, 256, 0, stream>>>(hsB, WqkvB, csB, phs, Qb, Kb, Vraw);
  vtrans<<<256, 256, 0, stream>>>(Vraw, VTb);
  attn_kernel<<<512, 512, 0, stream>>>(Qb, Kb, VTb, Ao);
  gemm_bt_f32<<<512, 256, 0, stream>>>(Ao, WoB, out, 2048, 2048, 16, 512);
}

// Round 16
// 208.476 us; speedup vs baseline: 1.4758x; 1.4758x over previous
//
#include <hip/hip_runtime.h>
#include <stdint.h>

typedef unsigned short u16;
typedef short short8 __attribute__((ext_vector_type(8)));
typedef float f32x4 __attribute__((ext_vector_type(4)));
typedef uint32_t u32x4 __attribute__((ext_vector_type(4)));

#define S_LEN 2048
#define NQH 32
#define NKH 8
#define DHD 64
#define MNEG -1.0e30f

__device__ __forceinline__ float b2f(u16 u){
  union { uint32_t i; float f; } c; c.i = ((uint32_t)u) << 16; return c.f;
}
__device__ __forceinline__ u16 f2b(float f){
  union { float f; uint32_t i; } c; c.f = f;
  uint32_t r = c.i + 0x7fffu + ((c.i >> 16) & 1u);
  return (u16)(r >> 16);
}
__device__ __forceinline__ uint32_t cvt_pk_bf16(float lo, float hi){
  uint32_t r;
  asm("v_cvt_pk_bf16_f32 %0, %1, %2" : "=v"(r) : "v"(lo), "v"(hi));
  return r;
}
__device__ __forceinline__ void gload_lds16(const void* g, void* l){
  __builtin_amdgcn_global_load_lds((const __attribute__((address_space(1))) uint32_t*)g,
                                   (__attribute__((address_space(3))) uint32_t*)l, 16, 0, 0);
}

// ------- fused fp32 -> bf16 convert (hs | Wqkv | Wo) + cos/sin bf16 pack -------
__global__ __launch_bounds__(256) void cvt_all(const float* __restrict__ hs,
                                               const float* __restrict__ wq,
                                               const float* __restrict__ wo,
                                               const float* __restrict__ cosp,
                                               const float* __restrict__ sinp,
                                               u16* __restrict__ hsB,
                                               u16* __restrict__ wqB,
                                               u16* __restrict__ woB,
                                               uint32_t* __restrict__ csB){
  int i = blockIdx.x * 256 + threadIdx.x;       // 4718592 f32x4 + 32768 cs-x4
  if (i >= 4718592){
    int off = i - 4718592;                      // 0..32767
    float4 c = ((const float4*)cosp)[off];
    float4 s = ((const float4*)sinp)[off];
    u32x4 o = { (uint32_t)f2b(c.x) | ((uint32_t)f2b(s.x) << 16),
                (uint32_t)f2b(c.y) | ((uint32_t)f2b(s.y) << 16),
                (uint32_t)f2b(c.z) | ((uint32_t)f2b(s.z) << 16),
                (uint32_t)f2b(c.w) | ((uint32_t)f2b(s.w) << 16) };
    ((u32x4*)csB)[off] = o;
    return;
  }
  const float* src; u16* dst; int off;
  if (i < 2097152)      { src = hs; dst = hsB; off = i; }
  else if (i < 3670016) { src = wq; dst = wqB; off = i - 2097152; }
  else                  { src = wo; dst = woB; off = i - 3670016; }
  float4 v = ((const float4*)src)[off];
  uint2 o;
  o.x = (uint32_t)f2b(v.x) | ((uint32_t)f2b(v.y) << 16);
  o.y = (uint32_t)f2b(v.z) | ((uint32_t)f2b(v.w) << 16);
  ((uint2*)dst)[off] = o;
}

// ---- GEMM staging (512 threads): A 128x64 (2 issues) + B 128x64 (2 issues) ----
// Per-wave LDS dest = wave-uniform base + lane*16 (gload_lds-safe; attn-verified).
#define GSTAGE(KT, BSEL) do { \
    _Pragma("unroll") \
    for (int i_ = 0; i_ < 2; ++i_){ \
      const int row_ = i_ * 64 + (tid >> 3); \
      const int ch_  = tid & 7; \
      const int gc_  = ((ch_ ^ (row_ & 7)) << 4); \
      gload_lds16((const char*)A + (size_t)(m0 + row_) * ldb + (size_t)(KT) * 128 + gc_, \
                  (char*)lA + (BSEL) * 16384 + row_ * 128 + ch_ * 16); \
    } \
    _Pragma("unroll") \
    for (int i_ = 0; i_ < 2; ++i_){ \
      const int row_ = i_ * 64 + (tid >> 3); \
      const int ch_  = tid & 7; \
      const int gc_  = ((ch_ ^ (row_ & 7)) << 4); \
      gload_lds16((const char*)Bm + (size_t)(n0 + row_) * ldb + (size_t)(KT) * 128 + gc_, \
                  (char*)lB + (BSEL) * 16384 + row_ * 128 + ch_ * 16); \
    } \
  } while (0)

// ---- compute body (8 waves, 4Mx2N): wave tile 32x64, acc[2][4] ----
#define GCOMPUTE(CUR) do { \
    _Pragma("unroll") \
    for (int kk = 0; kk < 2; ++kk){ \
      short8 af[2], bfr[4]; \
      _Pragma("unroll") \
      for (int mi = 0; mi < 2; ++mi){ \
        const int row = wm * 32 + mi * 16 + lc; \
        const int cc = (kk * 4 + lg) ^ (row & 7); \
        af[mi] = *(const short8*)((const char*)lA + (CUR) * 16384 + row * 128 + cc * 16); \
      } \
      _Pragma("unroll") \
      for (int ni = 0; ni < 4; ++ni){ \
        const int row = wn * 64 + ni * 16 + lc; \
        const int cc = (kk * 4 + lg) ^ (row & 7); \
        bfr[ni] = *(const short8*)((const char*)lB + (CUR) * 16384 + row * 128 + cc * 16); \
      } \
      _Pragma("unroll") \
      for (int mi = 0; mi < 2; ++mi) \
        _Pragma("unroll") \
        for (int ni = 0; ni < 4; ++ni) \
          acc[mi][ni] = __builtin_amdgcn_mfma_f32_16x16x32_bf16(af[mi], bfr[ni], acc[mi][ni], 0, 0, 0); \
    } \
  } while (0)

// ---------------- bf16 GEMM (f32 out): 128^2 tile, 8 waves, 2-buffer 1-ahead ----------------
// { STAGE(kt+1 -> buf^1); vmcnt(4); barrier; compute(buf); barrier }.
// 64KB LDS -> 2 blocks/CU x 8 waves = 16 waves/CU (2x R14's TLP).
__global__ __launch_bounds__(512)
void gemm_bt_f32(const u16* __restrict__ A, const u16* __restrict__ Bm,
                 float* __restrict__ Cp, int N, int K, int nbx, int nwg)
{
  __shared__ alignas(16) u16 lA[2 * 128 * 64];
  __shared__ alignas(16) u16 lB[2 * 128 * 64];
  const int id = blockIdx.x;
  const int swz = (id & 7) * (nwg >> 3) + (id >> 3);
  const int m0 = (swz / nbx) * 128, n0 = (swz % nbx) * 128;
  const int tid = threadIdx.x;
  const int w = tid >> 6, l = tid & 63;
  const int lg = l >> 4, lc = l & 15;
  const int wm = w >> 1, wn = w & 1;
  const size_t ldb = (size_t)K * 2;   // row bytes
  f32x4 acc[2][4] = {};
  const int kiters = K >> 6;

  GSTAGE(0, 0);
  for (int kt = 0; kt < kiters; ++kt){
    const int cur = kt & 1;
    if (kt + 1 < kiters){
      GSTAGE(kt + 1, cur ^ 1);
      asm volatile("s_waitcnt vmcnt(4)" ::: "memory");   // tile-kt loads landed
    } else {
      asm volatile("s_waitcnt vmcnt(0)" ::: "memory");
    }
    __builtin_amdgcn_s_barrier();
    GCOMPUTE(cur);
    __builtin_amdgcn_s_barrier();
  }
  const int r0 = m0 + wm * 32 + lg * 4;
  const int c0 = n0 + wn * 64 + lc;
#pragma unroll
  for (int mi = 0; mi < 2; ++mi)
#pragma unroll
    for (int ni = 0; ni < 4; ++ni)
#pragma unroll
      for (int j = 0; j < 4; ++j)
        Cp[(size_t)(r0 + mi * 16 + j) * (size_t)N + (size_t)(c0 + ni * 16)] = acc[mi][ni][j];
}

// ---------------- GEMM1 + fused RoPE/scale epilogue (8 waves) ----------------
// qkv = hs * Wqkv^T (M=4096, N=3072, K=2048). Per thread: one head (wn), 4
// d-positions {lc+16ni}; RoPE partner d^32 = acc[mi][ni^2][j] (same thread).
// Q *1.2*kscale*phs -> Qb; K *1.2 -> Kb; V raw -> Vraw[b][s][8][64].
__global__ __launch_bounds__(512)
void gemm1_rope(const u16* __restrict__ A, const u16* __restrict__ Bm,
                const uint32_t* __restrict__ cs, const float* __restrict__ phs,
                u16* __restrict__ Qo, u16* __restrict__ Ko, u16* __restrict__ Vraw)
{
  __shared__ alignas(16) u16 lA[2 * 128 * 64];
  __shared__ alignas(16) u16 lB[2 * 128 * 64];
  const int id = blockIdx.x;
  const int swz = (id & 7) * 96 + (id >> 3);   // nwg = 768
  const int m0 = (swz / 24) * 128, n0 = (swz % 24) * 128;
  const int tid = threadIdx.x;
  const int w = tid >> 6, l = tid & 63;
  const int lg = l >> 4, lc = l & 15;
  const int wm = w >> 1, wn = w & 1;
  const size_t ldb = 4096;            // K=2048 row bytes
  f32x4 acc[2][4] = {};

  GSTAGE(0, 0);
  for (int kt = 0; kt < 32; ++kt){
    const int cur = kt & 1;
    if (kt + 1 < 32){
      GSTAGE(kt + 1, cur ^ 1);
      asm volatile("s_waitcnt vmcnt(4)" ::: "memory");
    } else {
      asm volatile("s_waitcnt vmcnt(0)" ::: "memory");
    }
    __builtin_amdgcn_s_barrier();
    GCOMPUTE(cur);
    __builtin_amdgcn_s_barrier();
  }
  const int r0 = m0 + wm * 32 + lg * 4;
  const int c0 = n0 + wn * 64 + lc;
  const int head = (n0 + wn * 64) >> 6;          // one head per thread
  const int b = m0 >> 11;
  if (head < 40){
    const float scale = (head < NQH) ? 1.2f * 0.18033688011112042f * phs[b * NQH + head] : 1.2f;
    u16* dstbase = (head < NQH)
        ? (Qo + ((size_t)(b * NQH + head) * S_LEN) * 64)
        : (Ko + ((size_t)(b * NKH + (head - NQH)) * S_LEN) * 64);
#pragma unroll
    for (int mi = 0; mi < 2; ++mi)
#pragma unroll
      for (int j = 0; j < 4; ++j){
        const int s = (r0 + mi * 16 + j) & 2047;
        const uint32_t* csrow = cs + s * 64;
        float xs[4] = {acc[mi][0][j], acc[mi][1][j], acc[mi][2][j], acc[mi][3][j]};
#pragma unroll
        for (int ni = 0; ni < 4; ++ni){
          const int d = lc + ni * 16;
          const uint32_t csv = csrow[d];
          const float cv = b2f((u16)(csv & 0xffff));
          const float sv = b2f((u16)(csv >> 16));
          const float sgn = (ni < 2) ? -1.f : 1.f;
          const float v = (xs[ni] * cv + sgn * xs[ni ^ 2] * sv) * scale;
          dstbase[(size_t)s * 64 + d] = f2b(v);
        }
      }
  } else {
    // V heads -> compact Vraw[b][s][8][64]
#pragma unroll
    for (int mi = 0; mi < 2; ++mi)
#pragma unroll
      for (int ni = 0; ni < 4; ++ni)
#pragma unroll
        for (int j = 0; j < 4; ++j){
          const int r = r0 + mi * 16 + j;
          Vraw[(size_t)r * 512 + (c0 + ni * 16 - 2560)] = f2b(acc[mi][ni][j]);
        }
  }
}
#undef GSTAGE
#undef GCOMPUTE

// ---------------- V transpose + k-permute: Vraw[b][s][8][64] -> VT[b][kh][d][t*128+k] ----------------
// VT[d][t*128+k] = V[s = t*128 + h(k)][d], h(k) = 32*(k>>5) + 16*((k>>2)&1)
// + 4*((k>>3)&3) + (k&3) -> zero-shuffle PV in attention.
__global__ __launch_bounds__(256)
void vtrans(const u16* __restrict__ Vraw, u16* __restrict__ VT)
{
  int bid = blockIdx.x;                 // (b*8+kh)*16 + t
  int t = bid & 15, kh = (bid >> 4) & 7, b = bid >> 7;
  __shared__ u16 vlds[128][72];
  int tid = threadIdx.x;
  {
    int r = tid >> 1, half = tid & 1;
    const u16* src = Vraw + (((size_t)(b * S_LEN + t * 128 + r) * 8 + kh) << 6) + half * 32;
    uint4 a0 = *(const uint4*)(src);
    uint4 a1 = *(const uint4*)(src + 8);
    uint4 a2 = *(const uint4*)(src + 16);
    uint4 a3 = *(const uint4*)(src + 24);
    *(uint4*)&vlds[r][half * 32]      = a0;
    *(uint4*)&vlds[r][half * 32 + 8]  = a1;
    *(uint4*)&vlds[r][half * 32 + 16] = a2;
    *(uint4*)&vlds[r][half * 32 + 24] = a3;
  }
  __syncthreads();
  const int d = tid >> 2, kk2 = tid & 3;
  u16* dst = VT + ((size_t)(b * NKH + kh) * 64 + d) * S_LEN + t * 128 + kk2 * 32;
#pragma unroll
  for (int j = 0; j < 4; ++j){          // j = lg
    u16 o[8];
#pragma unroll
    for (int e = 0; e < 8; ++e){
      const int hk = kk2 * 32 + ((e >> 2) << 4) + j * 4 + (e & 3);
      o[e] = vlds[hk][d];
    }
    uint4 ov = { (uint32_t)o[0] | ((uint32_t)o[1] << 16), (uint32_t)o[2] | ((uint32_t)o[3] << 16),
                 (uint32_t)o[4] | ((uint32_t)o[5] << 16), (uint32_t)o[6] | ((uint32_t)o[7] << 16) };
    *(uint4*)(dst + j * 8) = ov;
  }
}

// ---------------- attention helper: softmax + pack (zero-shuffle PV) ----------------
__device__ __forceinline__ void proc_chunk(f32x4 (&sv)[8], float& mrow, float& lsum,
                                           f32x4 (&o)[4], uint32_t (&pw)[4][4],
                                           const int lg, const int lc,
                                           const bool diag, const int qloc)
{
  if (diag){
#pragma unroll
    for (int nj = 0; nj < 8; ++nj)
#pragma unroll
      for (int jj = 0; jj < 4; ++jj){
        const int kloc = nj * 16 + lg * 4 + jj;
        if (kloc > qloc) sv[nj][jj] = MNEG;
      }
  }
  float mu = sv[0][0];
#pragma unroll
  for (int nj = 0; nj < 8; ++nj)
#pragma unroll
    for (int jj = 0; jj < 4; ++jj) mu = fmaxf(mu, sv[nj][jj]);
  mu = fmaxf(mu, __shfl_xor(mu, 16));
  mu = fmaxf(mu, __shfl_xor(mu, 32));
  if (!__all(mu <= mrow + 11.54f)){
    const float mnew = fmaxf(mrow, mu);
    const float sf = __builtin_amdgcn_exp2f(mrow - mnew);
    mrow = mnew;
    lsum *= sf;
#pragma unroll
    for (int dn = 0; dn < 4; ++dn)
#pragma unroll
      for (int jj = 0; jj < 4; ++jj) o[dn][jj] *= sf;
  }
  const float mcur = mrow;
  float ps = 0.f;
#pragma unroll
  for (int nj = 0; nj < 8; ++nj)
#pragma unroll
    for (int jj = 0; jj < 4; ++jj){
      const float pv = __builtin_amdgcn_exp2f(sv[nj][jj] - mcur);
      sv[nj][jj] = pv;
      ps += pv;
    }
  lsum += ps;
#pragma unroll
  for (int kk2 = 0; kk2 < 4; ++kk2){
    pw[kk2][0] = cvt_pk_bf16(sv[kk2 * 2][0],     sv[kk2 * 2][1]);
    pw[kk2][1] = cvt_pk_bf16(sv[kk2 * 2][2],     sv[kk2 * 2][3]);
    pw[kk2][2] = cvt_pk_bf16(sv[kk2 * 2 + 1][0], sv[kk2 * 2 + 1][1]);
    pw[kk2][3] = cvt_pk_bf16(sv[kk2 * 2 + 1][2], sv[kk2 * 2 + 1][3]);
  }
}

__device__ __forceinline__ short8 pw_frag(const uint32_t* pw){
  u32x4 v = { pw[0], pw[1], pw[2], pw[3] };
  return __builtin_bit_cast(short8, v);
}

// ---------------- causal GQA flash attention (R11-verified) ----------------
__global__ __launch_bounds__(512, 2)
void attn_kernel(const u16* __restrict__ Q, const u16* __restrict__ Kr,
                 const u16* __restrict__ VT, u16* __restrict__ Ao)
{
  int bid = blockIdx.x;
  int p  = bid & 15;
  int gp = (bid >> 4) & 1;
  int kh = (bid >> 5) & 7;
  int b  = bid >> 8;
  const int qt0 = p, qt1 = 31 - p;

  __shared__ alignas(16) u16 lK[2][128 * 64];
  __shared__ alignas(16) u16 lV[2][64 * 128];

  const int tid = threadIdx.x;
  const int hh = tid >> 8;
  const int h  = kh * 4 + gp * 2 + hh;
  const int w  = (tid >> 6) & 3;
  const int l  = tid & 63;
  const int lg = l >> 4, lc = l & 15;

  short8 qf[2][2];
  {
    const u16* qbase = Q + ((size_t)(b * NQH + h) * S_LEN) * 64;
#pragma unroll
    for (int kk = 0; kk < 2; ++kk){
      qf[0][kk] = *(const short8*)(qbase + (size_t)(qt0 * 64 + w * 16 + lc) * 64 + kk * 32 + lg * 8);
      qf[1][kk] = *(const short8*)(qbase + (size_t)(qt1 * 64 + w * 16 + lc) * 64 + kk * 32 + lg * 8);
    }
  }

  const u16* Kb = Kr + (size_t)(b * NKH + kh) * S_LEN * 64;
  const u16* Vb = VT + (size_t)(b * NKH + kh) * 64 * S_LEN;

  f32x4 o[2][4] = {};
  float mrow[2] = {MNEG, MNEG};
  float lsum[2] = {0.f, 0.f};

  const int nt = (qt1 >> 1) + 1;
  const int nt0 = qt0 >> 1;

#define STAGE(T, BSEL) do { \
    _Pragma("unroll") \
    for (int i_ = 0; i_ < 2; ++i_){ \
      const int row_ = i_ * 64 + (tid >> 3); \
      const int ch_  = tid & 7; \
      const int gc_  = ((ch_ ^ (row_ & 7)) << 4); \
      gload_lds16((const char*)(Kb + (size_t)((T) * 128 + row_) * 64) + gc_, \
                  (char*)lK[BSEL] + row_ * 128 + ch_ * 16); \
    } \
    _Pragma("unroll") \
    for (int i_ = 0; i_ < 2; ++i_){ \
      const int row_ = i_ * 32 + (tid >> 4); \
      const int ch_  = tid & 15; \
      const int gc_  = ((ch_ ^ (row_ & 15)) << 4); \
      gload_lds16((const char*)(Vb + (size_t)row_ * S_LEN + (T) * 128) + gc_, \
                  (char*)lV[BSEL] + row_ * 256 + ch_ * 16); \
    } \
  } while (0)

  STAGE(0, 0);

  for (int t = 0; t < nt; ++t){
    const int cur = t & 1;
    const bool act0 = (t <= nt0);
    if (t + 1 < nt){
      STAGE(t + 1, cur ^ 1);
      asm volatile("s_waitcnt vmcnt(4)" ::: "memory");
    } else {
      asm volatile("s_waitcnt vmcnt(0)" ::: "memory");
    }
    __builtin_amdgcn_s_barrier();

    f32x4 sv[2][8] = {};
    __builtin_amdgcn_s_setprio(1);
#pragma unroll
    for (int kk = 0; kk < 2; ++kk){
      short8 kf[8];
#pragma unroll
      for (int nj = 0; nj < 8; ++nj){
        const int row = nj * 16 + lc;
        const int cc = (kk * 4 + lg) ^ (row & 7);
        kf[nj] = *(const short8*)((const char*)lK[cur] + row * 128 + cc * 16);
      }
      if (act0)
#pragma unroll
        for (int nj = 0; nj < 8; ++nj)
          sv[0][nj] = __builtin_amdgcn_mfma_f32_16x16x32_bf16(kf[nj], qf[0][kk], sv[0][nj], 0, 0, 0);
#pragma unroll
      for (int nj = 0; nj < 8; ++nj)
        sv[1][nj] = __builtin_amdgcn_mfma_f32_16x16x32_bf16(kf[nj], qf[1][kk], sv[1][nj], 0, 0, 0);
    }
    __builtin_amdgcn_s_setprio(0);

    uint32_t pw[2][4][4];
    if (act0)
      proc_chunk(sv[0], mrow[0], lsum[0], o[0], pw[0], lg, lc,
                 t == (qt0 >> 1), (qt0 & 1) * 64 + w * 16 + lc);
    proc_chunk(sv[1], mrow[1], lsum[1], o[1], pw[1], lg, lc,
               t == (qt1 >> 1), (qt1 & 1) * 64 + w * 16 + lc);

    __builtin_amdgcn_s_setprio(1);
#pragma unroll
    for (int kk2 = 0; kk2 < 4; ++kk2){
      short8 vf[4];
#pragma unroll
      for (int dn = 0; dn < 4; ++dn){
        const int row = dn * 16 + lc;
        const int cc = (kk2 * 4 + lg) ^ (row & 15);
        vf[dn] = *(const short8*)((const char*)lV[cur] + row * 256 + cc * 16);
      }
      if (act0){
        const short8 pb0 = pw_frag(pw[0][kk2]);
#pragma unroll
        for (int dn = 0; dn < 4; ++dn)
          o[0][dn] = __builtin_amdgcn_mfma_f32_16x16x32_bf16(vf[dn], pb0, o[0][dn], 0, 0, 0);
      }
      const short8 pb1 = pw_frag(pw[1][kk2]);
#pragma unroll
      for (int dn = 0; dn < 4; ++dn)
        o[1][dn] = __builtin_amdgcn_mfma_f32_16x16x32_bf16(vf[dn], pb1, o[1][dn], 0, 0, 0);
    }
    __builtin_amdgcn_s_setprio(0);
    __builtin_amdgcn_s_barrier();
  }
#undef STAGE

#pragma unroll
  for (int c = 0; c < 2; ++c){
    const int qt = c ? qt1 : qt0;
    float ls = lsum[c];
    ls += __shfl_xor(ls, 16);
    ls += __shfl_xor(ls, 32);
    const float inv = 1.f / ls;
    const int sq = qt * 64 + w * 16 + lc;
#pragma unroll
    for (int dn = 0; dn < 4; ++dn){
      uint2 pk;
      pk.x = cvt_pk_bf16(o[c][dn][0] * inv, o[c][dn][1] * inv);
      pk.y = cvt_pk_bf16(o[c][dn][2] * inv, o[c][dn][3] * inv);
      const int col = h * 64 + dn * 16 + lg * 4;
      *(uint2*)&Ao[(size_t)(b * S_LEN + sq) * 2048 + col] = pk;
    }
  }
}

// ---------------- launcher ----------------
extern "C" void kernel_launch(void* const* d_in, const int* in_sizes, int n_in,
                              void* d_out, int out_size, void* d_ws, size_t ws_size,
                              hipStream_t stream)
{
  const float* cosT = (const float*)d_in[0];
  const float* sinT = (const float*)d_in[1];
  const float* hs   = (const float*)d_in[2];
  const float* phs  = (const float*)d_in[3];
  const float* Wqkv = (const float*)d_in[4];
  const float* Wo   = (const float*)d_in[5];
  float* out = (float*)d_out;
  char* ws = (char*)d_ws;

  u16* hsB   = (u16*)(ws);               // 16,777,216 B (aliased as attn_out later)
  u16* WqkvB = (u16*)(ws + 16777216);    // 12,582,912 B
  u16* WoB   = (u16*)(ws + 29360128);    //  8,388,608 B
  u16* Vraw  = (u16*)(ws + 37748736);    //  4,194,304 B
  u16* Qb    = (u16*)(ws + 41943040);    // 16,777,216 B
  u16* Kb    = (u16*)(ws + 58720256);    //  4,194,304 B
  u16* VTb   = (u16*)(ws + 62914560);    //  4,194,304 B
  uint32_t* csB = (uint32_t*)(ws + 67108864); // 524,288 B (total 67,633,152 B)
  u16* Ao    = hsB;                      // hsB dead after GEMM1

  cvt_all<<<18560, 256, 0, stream>>>(hs, Wqkv, Wo, cosT, sinT, hsB, WqkvB, WoB, csB);
  gemm1_rope<<<768, 512, 0, stream>>>(hsB, WqkvB, csB, phs, Qb, Kb, Vraw);
  vtrans<<<256, 256, 0, stream>>>(Vraw, VTb);
  attn_kernel<<<512, 512, 0, stream>>>(Qb, Kb, VTb, Ao);
  gemm_bt_f32<<<512, 512, 0, stream>>>(Ao, WoB, out, 2048, 2048, 16, 512);
}

// Round 17
// 203.760 us; speedup vs baseline: 1.5099x; 1.0231x over previous
//
#include <hip/hip_runtime.h>
#include <stdint.h>

typedef unsigned short u16;
typedef short short8 __attribute__((ext_vector_type(8)));
typedef float f32x4 __attribute__((ext_vector_type(4)));
typedef uint32_t u32x4 __attribute__((ext_vector_type(4)));

#define S_LEN 2048
#define NQH 32
#define NKH 8
#define DHD 64
#define MNEG -1.0e30f

__device__ __forceinline__ float b2f(u16 u){
  union { uint32_t i; float f; } c; c.i = ((uint32_t)u) << 16; return c.f;
}
__device__ __forceinline__ u16 f2b(float f){
  union { float f; uint32_t i; } c; c.f = f;
  uint32_t r = c.i + 0x7fffu + ((c.i >> 16) & 1u);
  return (u16)(r >> 16);
}
__device__ __forceinline__ uint32_t cvt_pk_bf16(float lo, float hi){
  uint32_t r;
  asm("v_cvt_pk_bf16_f32 %0, %1, %2" : "=v"(r) : "v"(lo), "v"(hi));
  return r;
}
__device__ __forceinline__ void gload_lds16(const void* g, void* l){
  __builtin_amdgcn_global_load_lds((const __attribute__((address_space(1))) uint32_t*)g,
                                   (__attribute__((address_space(3))) uint32_t*)l, 16, 0, 0);
}

// ------- fused fp32 -> bf16 convert (hs | Wqkv | Wo) + cos/sin bf16 pack -------
__global__ __launch_bounds__(256) void cvt_all(const float* __restrict__ hs,
                                               const float* __restrict__ wq,
                                               const float* __restrict__ wo,
                                               const float* __restrict__ cosp,
                                               const float* __restrict__ sinp,
                                               u16* __restrict__ hsB,
                                               u16* __restrict__ wqB,
                                               u16* __restrict__ woB,
                                               uint32_t* __restrict__ csB){
  int i = blockIdx.x * 256 + threadIdx.x;       // 4718592 f32x4 + 32768 cs-x4
  if (i >= 4718592){
    int off = i - 4718592;                      // 0..32767
    float4 c = ((const float4*)cosp)[off];
    float4 s = ((const float4*)sinp)[off];
    u32x4 o = { (uint32_t)f2b(c.x) | ((uint32_t)f2b(s.x) << 16),
                (uint32_t)f2b(c.y) | ((uint32_t)f2b(s.y) << 16),
                (uint32_t)f2b(c.z) | ((uint32_t)f2b(s.z) << 16),
                (uint32_t)f2b(c.w) | ((uint32_t)f2b(s.w) << 16) };
    ((u32x4*)csB)[off] = o;
    return;
  }
  const float* src; u16* dst; int off;
  if (i < 2097152)      { src = hs; dst = hsB; off = i; }
  else if (i < 3670016) { src = wq; dst = wqB; off = i - 2097152; }
  else                  { src = wo; dst = woB; off = i - 3670016; }
  float4 v = ((const float4*)src)[off];
  uint2 o;
  o.x = (uint32_t)f2b(v.x) | ((uint32_t)f2b(v.y) << 16);
  o.y = (uint32_t)f2b(v.z) | ((uint32_t)f2b(v.w) << 16);
  ((uint2*)dst)[off] = o;
}

// ---- GEMM staging (512 threads): A 128x64 (2 issues) + B 128x64 (2 issues) ----
#define GSTAGE(KT, BSEL) do { \
    _Pragma("unroll") \
    for (int i_ = 0; i_ < 2; ++i_){ \
      const int row_ = i_ * 64 + (tid >> 3); \
      const int ch_  = tid & 7; \
      const int gc_  = ((ch_ ^ (row_ & 7)) << 4); \
      gload_lds16((const char*)A + (size_t)(m0 + row_) * ldb + (size_t)(KT) * 128 + gc_, \
                  (char*)lA + (BSEL) * 16384 + row_ * 128 + ch_ * 16); \
    } \
    _Pragma("unroll") \
    for (int i_ = 0; i_ < 2; ++i_){ \
      const int row_ = i_ * 64 + (tid >> 3); \
      const int ch_  = tid & 7; \
      const int gc_  = ((ch_ ^ (row_ & 7)) << 4); \
      gload_lds16((const char*)Bm + (size_t)(n0 + row_) * ldb + (size_t)(KT) * 128 + gc_, \
                  (char*)lB + (BSEL) * 16384 + row_ * 128 + ch_ * 16); \
    } \
  } while (0)

// ---- compute body (8 waves, 4Mx2N): wave tile 32x64, acc[2][4] ----
#define GCOMPUTE(CUR) do { \
    _Pragma("unroll") \
    for (int kk = 0; kk < 2; ++kk){ \
      short8 af[2], bfr[4]; \
      _Pragma("unroll") \
      for (int mi = 0; mi < 2; ++mi){ \
        const int row = wm * 32 + mi * 16 + lc; \
        const int cc = (kk * 4 + lg) ^ (row & 7); \
        af[mi] = *(const short8*)((const char*)lA + (CUR) * 16384 + row * 128 + cc * 16); \
      } \
      _Pragma("unroll") \
      for (int ni = 0; ni < 4; ++ni){ \
        const int row = wn * 64 + ni * 16 + lc; \
        const int cc = (kk * 4 + lg) ^ (row & 7); \
        bfr[ni] = *(const short8*)((const char*)lB + (CUR) * 16384 + row * 128 + cc * 16); \
      } \
      _Pragma("unroll") \
      for (int mi = 0; mi < 2; ++mi) \
        _Pragma("unroll") \
        for (int ni = 0; ni < 4; ++ni) \
          acc[mi][ni] = __builtin_amdgcn_mfma_f32_16x16x32_bf16(af[mi], bfr[ni], acc[mi][ni], 0, 0, 0); \
    } \
  } while (0)

// ---------------- bf16 GEMM (f32 out): 128^2 tile, 8 waves, 2-buffer 1-ahead ----------------
__global__ __launch_bounds__(512)
void gemm_bt_f32(const u16* __restrict__ A, const u16* __restrict__ Bm,
                 float* __restrict__ Cp, int N, int K, int nbx, int nwg)
{
  __shared__ alignas(16) u16 lA[2 * 128 * 64];
  __shared__ alignas(16) u16 lB[2 * 128 * 64];
  const int id = blockIdx.x;
  const int swz = (id & 7) * (nwg >> 3) + (id >> 3);
  const int m0 = (swz / nbx) * 128, n0 = (swz % nbx) * 128;
  const int tid = threadIdx.x;
  const int w = tid >> 6, l = tid & 63;
  const int lg = l >> 4, lc = l & 15;
  const int wm = w >> 1, wn = w & 1;
  const size_t ldb = (size_t)K * 2;   // row bytes
  f32x4 acc[2][4] = {};
  const int kiters = K >> 6;

  GSTAGE(0, 0);
  for (int kt = 0; kt < kiters; ++kt){
    const int cur = kt & 1;
    if (kt + 1 < kiters){
      GSTAGE(kt + 1, cur ^ 1);
      asm volatile("s_waitcnt vmcnt(4)" ::: "memory");   // tile-kt loads landed
    } else {
      asm volatile("s_waitcnt vmcnt(0)" ::: "memory");
    }
    __builtin_amdgcn_s_barrier();
    GCOMPUTE(cur);
    __builtin_amdgcn_s_barrier();
  }
  const int r0 = m0 + wm * 32 + lg * 4;
  const int c0 = n0 + wn * 64 + lc;
#pragma unroll
  for (int mi = 0; mi < 2; ++mi)
#pragma unroll
    for (int ni = 0; ni < 4; ++ni)
#pragma unroll
      for (int j = 0; j < 4; ++j)
        Cp[(size_t)(r0 + mi * 16 + j) * (size_t)N + (size_t)(c0 + ni * 16)] = acc[mi][ni][j];
}

// ---------------- GEMM1 + fused RoPE/scale epilogue (8 waves) ----------------
__global__ __launch_bounds__(512)
void gemm1_rope(const u16* __restrict__ A, const u16* __restrict__ Bm,
                const uint32_t* __restrict__ cs, const float* __restrict__ phs,
                u16* __restrict__ Qo, u16* __restrict__ Ko, u16* __restrict__ Vraw)
{
  __shared__ alignas(16) u16 lA[2 * 128 * 64];
  __shared__ alignas(16) u16 lB[2 * 128 * 64];
  const int id = blockIdx.x;
  const int swz = (id & 7) * 96 + (id >> 3);   // nwg = 768
  const int m0 = (swz / 24) * 128, n0 = (swz % 24) * 128;
  const int tid = threadIdx.x;
  const int w = tid >> 6, l = tid & 63;
  const int lg = l >> 4, lc = l & 15;
  const int wm = w >> 1, wn = w & 1;
  const size_t ldb = 4096;            // K=2048 row bytes
  f32x4 acc[2][4] = {};

  GSTAGE(0, 0);
  for (int kt = 0; kt < 32; ++kt){
    const int cur = kt & 1;
    if (kt + 1 < 32){
      GSTAGE(kt + 1, cur ^ 1);
      asm volatile("s_waitcnt vmcnt(4)" ::: "memory");
    } else {
      asm volatile("s_waitcnt vmcnt(0)" ::: "memory");
    }
    __builtin_amdgcn_s_barrier();
    GCOMPUTE(cur);
    __builtin_amdgcn_s_barrier();
  }
  const int r0 = m0 + wm * 32 + lg * 4;
  const int c0 = n0 + wn * 64 + lc;
  const int head = (n0 + wn * 64) >> 6;          // one head per thread
  const int b = m0 >> 11;
  if (head < 40){
    const float scale = (head < NQH) ? 1.2f * 0.18033688011112042f * phs[b * NQH + head] : 1.2f;
    u16* dstbase = (head < NQH)
        ? (Qo + ((size_t)(b * NQH + head) * S_LEN) * 64)
        : (Ko + ((size_t)(b * NKH + (head - NQH)) * S_LEN) * 64);
#pragma unroll
    for (int mi = 0; mi < 2; ++mi)
#pragma unroll
      for (int j = 0; j < 4; ++j){
        const int s = (r0 + mi * 16 + j) & 2047;
        const uint32_t* csrow = cs + s * 64;
        float xs[4] = {acc[mi][0][j], acc[mi][1][j], acc[mi][2][j], acc[mi][3][j]};
#pragma unroll
        for (int ni = 0; ni < 4; ++ni){
          const int d = lc + ni * 16;
          const uint32_t csv = csrow[d];
          const float cv = b2f((u16)(csv & 0xffff));
          const float sv = b2f((u16)(csv >> 16));
          const float sgn = (ni < 2) ? -1.f : 1.f;
          const float v = (xs[ni] * cv + sgn * xs[ni ^ 2] * sv) * scale;
          dstbase[(size_t)s * 64 + d] = f2b(v);
        }
      }
  } else {
    // V heads -> compact Vraw[b][s][8][64]
#pragma unroll
    for (int mi = 0; mi < 2; ++mi)
#pragma unroll
      for (int ni = 0; ni < 4; ++ni)
#pragma unroll
        for (int j = 0; j < 4; ++j){
          const int r = r0 + mi * 16 + j;
          Vraw[(size_t)r * 512 + (c0 + ni * 16 - 2560)] = f2b(acc[mi][ni][j]);
        }
  }
}
#undef GSTAGE
#undef GCOMPUTE

// ---------------- V transpose + k-permute: Vraw[b][s][8][64] -> VT[b][kh][d][t*128+k] ----------------
// VT[d][t*128+k] = V[s = t*128 + h(k)][d], h(k) = 32*(k>>5) + 16*((k>>2)&1)
// + 4*((k>>3)&3) + (k&3) -> zero-shuffle PV in attention.
__global__ __launch_bounds__(256)
void vtrans(const u16* __restrict__ Vraw, u16* __restrict__ VT)
{
  int bid = blockIdx.x;                 // (b*8+kh)*16 + t
  int t = bid & 15, kh = (bid >> 4) & 7, b = bid >> 7;
  __shared__ u16 vlds[128][72];
  int tid = threadIdx.x;
  {
    int r = tid >> 1, half = tid & 1;
    const u16* src = Vraw + (((size_t)(b * S_LEN + t * 128 + r) * 8 + kh) << 6) + half * 32;
    uint4 a0 = *(const uint4*)(src);
    uint4 a1 = *(const uint4*)(src + 8);
    uint4 a2 = *(const uint4*)(src + 16);
    uint4 a3 = *(const uint4*)(src + 24);
    *(uint4*)&vlds[r][half * 32]      = a0;
    *(uint4*)&vlds[r][half * 32 + 8]  = a1;
    *(uint4*)&vlds[r][half * 32 + 16] = a2;
    *(uint4*)&vlds[r][half * 32 + 24] = a3;
  }
  __syncthreads();
  const int d = tid >> 2, kk2 = tid & 3;
  u16* dst = VT + ((size_t)(b * NKH + kh) * 64 + d) * S_LEN + t * 128 + kk2 * 32;
#pragma unroll
  for (int j = 0; j < 4; ++j){          // j = lg
    u16 o[8];
#pragma unroll
    for (int e = 0; e < 8; ++e){
      const int hk = kk2 * 32 + ((e >> 2) << 4) + j * 4 + (e & 3);
      o[e] = vlds[hk][d];
    }
    uint4 ov = { (uint32_t)o[0] | ((uint32_t)o[1] << 16), (uint32_t)o[2] | ((uint32_t)o[3] << 16),
                 (uint32_t)o[4] | ((uint32_t)o[5] << 16), (uint32_t)o[6] | ((uint32_t)o[7] << 16) };
    *(uint4*)(dst + j * 8) = ov;
  }
}

// ---------------- attention helper: softmax + pack (zero-shuffle PV) ----------------
__device__ __forceinline__ void proc_chunk(f32x4 (&sv)[8], float& mrow, float& lsum,
                                           f32x4 (&o)[4], uint32_t (&pw)[4][4],
                                           const int lg, const int lc,
                                           const bool diag, const int qloc)
{
  if (diag){
#pragma unroll
    for (int nj = 0; nj < 8; ++nj)
#pragma unroll
      for (int jj = 0; jj < 4; ++jj){
        const int kloc = nj * 16 + lg * 4 + jj;
        if (kloc > qloc) sv[nj][jj] = MNEG;
      }
  }
  float mu = sv[0][0];
#pragma unroll
  for (int nj = 0; nj < 8; ++nj)
#pragma unroll
    for (int jj = 0; jj < 4; ++jj) mu = fmaxf(mu, sv[nj][jj]);
  mu = fmaxf(mu, __shfl_xor(mu, 16));
  mu = fmaxf(mu, __shfl_xor(mu, 32));
  if (!__all(mu <= mrow + 11.54f)){
    const float mnew = fmaxf(mrow, mu);
    const float sf = __builtin_amdgcn_exp2f(mrow - mnew);
    mrow = mnew;
    lsum *= sf;
#pragma unroll
    for (int dn = 0; dn < 4; ++dn)
#pragma unroll
      for (int jj = 0; jj < 4; ++jj) o[dn][jj] *= sf;
  }
  const float mcur = mrow;
  float ps = 0.f;
#pragma unroll
  for (int nj = 0; nj < 8; ++nj)
#pragma unroll
    for (int jj = 0; jj < 4; ++jj){
      const float pv = __builtin_amdgcn_exp2f(sv[nj][jj] - mcur);
      sv[nj][jj] = pv;
      ps += pv;
    }
  lsum += ps;
#pragma unroll
  for (int kk2 = 0; kk2 < 4; ++kk2){
    pw[kk2][0] = cvt_pk_bf16(sv[kk2 * 2][0],     sv[kk2 * 2][1]);
    pw[kk2][1] = cvt_pk_bf16(sv[kk2 * 2][2],     sv[kk2 * 2][3]);
    pw[kk2][2] = cvt_pk_bf16(sv[kk2 * 2 + 1][0], sv[kk2 * 2 + 1][1]);
    pw[kk2][3] = cvt_pk_bf16(sv[kk2 * 2 + 1][2], sv[kk2 * 2 + 1][3]);
  }
}

__device__ __forceinline__ short8 pw_frag(const uint32_t* pw){
  u32x4 v = { pw[0], pw[1], pw[2], pw[3] };
  return __builtin_bit_cast(short8, v);
}

// ---------------- causal GQA flash attention ----------------
// R16 structure with T15-lite reorder: proc(c0) -> PV(c0) -> proc(c1) ->
// PV(c1), so PV(c0)'s MFMAs retire under proc(c1)'s serial softmax VALU
// (separate pipes; wave doesn't read o[] until next rescale). vf reads are
// per-PV (swizzled, conflict-free).
__global__ __launch_bounds__(512, 2)
void attn_kernel(const u16* __restrict__ Q, const u16* __restrict__ Kr,
                 const u16* __restrict__ VT, u16* __restrict__ Ao)
{
  int bid = blockIdx.x;
  int p  = bid & 15;
  int gp = (bid >> 4) & 1;
  int kh = (bid >> 5) & 7;
  int b  = bid >> 8;
  const int qt0 = p, qt1 = 31 - p;

  __shared__ alignas(16) u16 lK[2][128 * 64];
  __shared__ alignas(16) u16 lV[2][64 * 128];

  const int tid = threadIdx.x;
  const int hh = tid >> 8;
  const int h  = kh * 4 + gp * 2 + hh;
  const int w  = (tid >> 6) & 3;
  const int l  = tid & 63;
  const int lg = l >> 4, lc = l & 15;

  short8 qf[2][2];
  {
    const u16* qbase = Q + ((size_t)(b * NQH + h) * S_LEN) * 64;
#pragma unroll
    for (int kk = 0; kk < 2; ++kk){
      qf[0][kk] = *(const short8*)(qbase + (size_t)(qt0 * 64 + w * 16 + lc) * 64 + kk * 32 + lg * 8);
      qf[1][kk] = *(const short8*)(qbase + (size_t)(qt1 * 64 + w * 16 + lc) * 64 + kk * 32 + lg * 8);
    }
  }

  const u16* Kb = Kr + (size_t)(b * NKH + kh) * S_LEN * 64;
  const u16* Vb = VT + (size_t)(b * NKH + kh) * 64 * S_LEN;

  f32x4 o[2][4] = {};
  float mrow[2] = {MNEG, MNEG};
  float lsum[2] = {0.f, 0.f};

  const int nt = (qt1 >> 1) + 1;
  const int nt0 = qt0 >> 1;

#define STAGE(T, BSEL) do { \
    _Pragma("unroll") \
    for (int i_ = 0; i_ < 2; ++i_){ \
      const int row_ = i_ * 64 + (tid >> 3); \
      const int ch_  = tid & 7; \
      const int gc_  = ((ch_ ^ (row_ & 7)) << 4); \
      gload_lds16((const char*)(Kb + (size_t)((T) * 128 + row_) * 64) + gc_, \
                  (char*)lK[BSEL] + row_ * 128 + ch_ * 16); \
    } \
    _Pragma("unroll") \
    for (int i_ = 0; i_ < 2; ++i_){ \
      const int row_ = i_ * 32 + (tid >> 4); \
      const int ch_  = tid & 15; \
      const int gc_  = ((ch_ ^ (row_ & 15)) << 4); \
      gload_lds16((const char*)(Vb + (size_t)row_ * S_LEN + (T) * 128) + gc_, \
                  (char*)lV[BSEL] + row_ * 256 + ch_ * 16); \
    } \
  } while (0)

// PV accumulate for one chunk: own vf reads (swizzled), 16 MFMA into o[C]
#define PVACC(C) do { \
    _Pragma("unroll") \
    for (int kk2 = 0; kk2 < 4; ++kk2){ \
      short8 vf[4]; \
      _Pragma("unroll") \
      for (int dn = 0; dn < 4; ++dn){ \
        const int row = dn * 16 + lc; \
        const int cc = (kk2 * 4 + lg) ^ (row & 15); \
        vf[dn] = *(const short8*)((const char*)lV[cur] + row * 256 + cc * 16); \
      } \
      const short8 pb = pw_frag(pw[C][kk2]); \
      _Pragma("unroll") \
      for (int dn = 0; dn < 4; ++dn) \
        o[C][dn] = __builtin_amdgcn_mfma_f32_16x16x32_bf16(vf[dn], pb, o[C][dn], 0, 0, 0); \
    } \
  } while (0)

  STAGE(0, 0);

  for (int t = 0; t < nt; ++t){
    const int cur = t & 1;
    const bool act0 = (t <= nt0);
    if (t + 1 < nt){
      STAGE(t + 1, cur ^ 1);
      asm volatile("s_waitcnt vmcnt(4)" ::: "memory");
    } else {
      asm volatile("s_waitcnt vmcnt(0)" ::: "memory");
    }
    __builtin_amdgcn_s_barrier();

    // S^T = K Q^T (shared kf across chunks)
    f32x4 sv[2][8] = {};
    __builtin_amdgcn_s_setprio(1);
#pragma unroll
    for (int kk = 0; kk < 2; ++kk){
      short8 kf[8];
#pragma unroll
      for (int nj = 0; nj < 8; ++nj){
        const int row = nj * 16 + lc;
        const int cc = (kk * 4 + lg) ^ (row & 7);
        kf[nj] = *(const short8*)((const char*)lK[cur] + row * 128 + cc * 16);
      }
      if (act0)
#pragma unroll
        for (int nj = 0; nj < 8; ++nj)
          sv[0][nj] = __builtin_amdgcn_mfma_f32_16x16x32_bf16(kf[nj], qf[0][kk], sv[0][nj], 0, 0, 0);
#pragma unroll
      for (int nj = 0; nj < 8; ++nj)
        sv[1][nj] = __builtin_amdgcn_mfma_f32_16x16x32_bf16(kf[nj], qf[1][kk], sv[1][nj], 0, 0, 0);
    }
    __builtin_amdgcn_s_setprio(0);

    uint32_t pw[2][4][4];
    if (act0){
      proc_chunk(sv[0], mrow[0], lsum[0], o[0], pw[0], lg, lc,
                 t == (qt0 >> 1), (qt0 & 1) * 64 + w * 16 + lc);
      __builtin_amdgcn_s_setprio(1);
      PVACC(0);                        // retires under proc(c1)'s VALU chain
      __builtin_amdgcn_s_setprio(0);
    }
    proc_chunk(sv[1], mrow[1], lsum[1], o[1], pw[1], lg, lc,
               t == (qt1 >> 1), (qt1 & 1) * 64 + w * 16 + lc);
    __builtin_amdgcn_s_setprio(1);
    PVACC(1);
    __builtin_amdgcn_s_setprio(0);
    __builtin_amdgcn_s_barrier();
  }
#undef PVACC
#undef STAGE

#pragma unroll
  for (int c = 0; c < 2; ++c){
    const int qt = c ? qt1 : qt0;
    float ls = lsum[c];
    ls += __shfl_xor(ls, 16);
    ls += __shfl_xor(ls, 32);
    const float inv = 1.f / ls;
    const int sq = qt * 64 + w * 16 + lc;
#pragma unroll
    for (int dn = 0; dn < 4; ++dn){
      uint2 pk;
      pk.x = cvt_pk_bf16(o[c][dn][0] * inv, o[c][dn][1] * inv);
      pk.y = cvt_pk_bf16(o[c][dn][2] * inv, o[c][dn][3] * inv);
      const int col = h * 64 + dn * 16 + lg * 4;
      *(uint2*)&Ao[(size_t)(b * S_LEN + sq) * 2048 + col] = pk;
    }
  }
}

// ---------------- launcher ----------------
extern "C" void kernel_launch(void* const* d_in, const int* in_sizes, int n_in,
                              void* d_out, int out_size, void* d_ws, size_t ws_size,
                              hipStream_t stream)
{
  const float* cosT = (const float*)d_in[0];
  const float* sinT = (const float*)d_in[1];
  const float* hs   = (const float*)d_in[2];
  const float* phs  = (const float*)d_in[3];
  const float* Wqkv = (const float*)d_in[4];
  const float* Wo   = (const float*)d_in[5];
  float* out = (float*)d_out;
  char* ws = (char*)d_ws;

  u16* hsB   = (u16*)(ws);               // 16,777,216 B (aliased as attn_out later)
  u16* WqkvB = (u16*)(ws + 16777216);    // 12,582,912 B
  u16* WoB   = (u16*)(ws + 29360128);    //  8,388,608 B
  u16* Vraw  = (u16*)(ws + 37748736);    //  4,194,304 B
  u16* Qb    = (u16*)(ws + 41943040);    // 16,777,216 B
  u16* Kb    = (u16*)(ws + 58720256);    //  4,194,304 B
  u16* VTb   = (u16*)(ws + 62914560);    //  4,194,304 B
  uint32_t* csB = (uint32_t*)(ws + 67108864); // 524,288 B (total 67,633,152 B)
  u16* Ao    = hsB;                      // hsB dead after GEMM1

  cvt_all<<<18560, 256, 0, stream>>>(hs, Wqkv, Wo, cosT, sinT, hsB, WqkvB, WoB, csB);
  gemm1_rope<<<768, 512, 0, stream>>>(hsB, WqkvB, csB, phs, Qb, Kb, Vraw);
  vtrans<<<256, 256, 0, stream>>>(Vraw, VTb);
  attn_kernel<<<512, 512, 0, stream>>>(Qb, Kb, VTb, Ao);
  gemm_bt_f32<<<512, 512, 0, stream>>>(Ao, WoB, out, 2048, 2048, 16, 512);
}